// Round 6
// baseline (343.277 us; speedup 1.0000x reference)
//
#include <hip/hip_runtime.h>
#include <hip/hip_fp16.h>

// Bilateral denoiser, 1080x1920x11 fp32 -> 1080x1920x3 fp32.
// d^2 <= 36 (113 taps). PY=2 y-stacked px/thread packed in v_pk_*_f32 (f2).
// Exact c^128 via 7 packed squarings (approx pows FAIL: epilogue ratio
// amplifies weight error by 1/EPS=1e4). Colors fp16 in LDS (linear in
// output, rel err ~5e-4 -> safe).
// BRANCHLESS inner loop: all 13 dx execute; pruned/out-of-window taps get
// lwK=-1e30 from the wave-uniform constant table -> w=0 exactly. This keeps
// the 13 ds_read_b128/b64 batchable (no s_cbranch fences) to hide the
// ~120cyc LDS latency. LDS 29.6KB -> 5 blocks/CU -> 20 waves/CU.

namespace {
constexpr int IMG_H = 1080;
constexpr int IMG_W = 1920;
constexpr int CHN   = 11;
constexpr int TLX   = 32;
constexpr int TLY   = 16;
constexpr int HALO  = 6;
constexpr int RX    = TLX + 2 * HALO;   // 44
constexpr int RY    = TLY + 2 * HALO;   // 28
constexpr int PY    = 2;
constexpr int R2MAX = 36;

constexpr double CD = -1.4426950408889634;   // -log2(e)

struct alignas(16) Tab {
    // [j+6][dx+6] -> {invdC p0, invdC p1, lwK p0, lwK p1}; dy_p = j - p
    float v[14][13][4];
    constexpr Tab() : v{} {
        for (int jj = 0; jj < 14; ++jj)
            for (int di = 0; di < 13; ++di)
                for (int p = 0; p < 2; ++p) {
                    const int dy = (jj - 6) - p, dx = di - 6;
                    const int d2 = dy * dy + dx * dx;
                    float ic, lwk;
                    if (d2 == 0) {            // center: ad==0; huge ic -> clamp
                        ic = -1e30f; lwk = 0.f;
                    } else if (d2 <= R2MAX) { // active tap
                        double s = (double)d2, x = s;
                        for (int it = 0; it < 60; ++it) x = 0.5 * (x + s / x);
                        ic  = (float)(CD / x);
                        lwk = (float)(0.5 * CD * d2);
                    } else {                  // masked: w forced to exactly 0
                        ic = (float)CD; lwk = -1e30f;
                    }
                    v[jj][di][p]     = ic;
                    v[jj][di][2 + p] = lwk;
                }
    }
};
}
__constant__ Tab TAB;

typedef float f2 __attribute__((ext_vector_type(2)));

__global__ __launch_bounds__(256, 5)
void bilateral_denoise_kernel(const float* __restrict__ in, float* __restrict__ out) {
    __shared__ float4  ldsA[RY * RX];       // {nrm0, nrm1, nrm2, z}  16 B
    __shared__ __half2 ldsC[RY * RX][2];    // {col01, col2_}          8 B

    const int lx  = threadIdx.x;
    const int ty  = threadIdx.y;
    const int bx0 = blockIdx.x * TLX;
    const int by0 = blockIdx.y * TLY;
    const int tid = ty * 32 + lx;

    // ---- stage tile + halo (OOB -> zeros => dot=0 => c^128=0 => w=0) ----
    for (int r = tid; r < RY * RX; r += 256) {
        const int ry = r / RX;
        const int rx = r - ry * RX;
        const int gy = by0 - HALO + ry;
        const int gx = bx0 - HALO + rx;
        float4 A = make_float4(0.f, 0.f, 0.f, 0.f);
        float c0 = 0.f, c1 = 0.f, c2 = 0.f;
        if ((unsigned)gy < (unsigned)IMG_H && (unsigned)gx < (unsigned)IMG_W) {
            const float* p = in + (gy * IMG_W + gx) * CHN;
            c0 = p[0]; c1 = p[1]; c2 = p[2];
            A.x = p[3]; A.y = p[4]; A.z = p[5]; A.w = p[9];
        }
        ldsA[r] = A;
        ldsC[r][0] = __floats2half2_rn(c0, c1);
        ldsC[r][1] = __floats2half2_rn(c2, 0.f);
    }
    __syncthreads();

    // ---- per-thread center state: 2 px packed as one f2 pair ----
    const int gx = bx0 + lx;
    const int crow = (ty * PY + HALO) * RX + HALO + lx;
    const float4 A0 = ldsA[crow];
    const float4 A1 = ldsA[crow + RX];
    const f2 cnx2 = {A0.x, A1.x};
    const f2 cny2 = {A0.y, A1.y};
    const f2 cnz2 = {A0.z, A1.z};
    const f2 cz2  = {A0.w, A1.w};
    f2 rdz2;
#pragma unroll
    for (int p = 0; p < PY; ++p) {
        const int gy = by0 + ty * PY + p;
        float dzv = 0.f;
        if (gy < IMG_H) dzv = in[(gy * IMG_W + gx) * CHN + 10];
        // dz<=0 -> rcp(0)=+inf -> rrc=-inf -> clamp to CD/EPS == 1/max(.,EPS)
        const float rv = __builtin_amdgcn_rcpf(fmaxf(dzv, 0.f));
        if (p == 0) rdz2.x = rv; else rdz2.y = rv;
    }
    f2 ax2 = (f2)(0.f), ay2 = (f2)(0.f), az2 = (f2)(0.f), aw2 = (f2)(0.f);

    const float RCLAMP = -14426.9504f;   // CD * 1e4 (== CD/EPS)

    // j = dy + p; no inner branches — table masks inactive taps (w=0).
#pragma unroll 1
    for (int j = -HALO; j <= HALO + PY - 1; ++j) {   // 14 rows
        const int rowb = (ty * PY + HALO + j) * RX + HALO + lx;
        const float* trow = &TAB.v[j + 6][0][0];
#pragma unroll
        for (int dxi = 0; dxi < 13; ++dxi) {
            const int dx = dxi - 6;
            const float4 T4 = *(const float4*)(trow + dxi * 4);   // s_load_x4
            const f2 ic2 = {T4.x, T4.y};
            const f2 lw2 = {T4.z, T4.w};
            const float4 A = ldsA[rowb + dx];                     // ds_read_b128
            const __half2 h01 = ldsC[rowb + dx][0];               // ds_read_b64
            const __half2 h2x = ldsC[rowb + dx][1];
            const float c0 = __low2float(h01);
            const float c1 = __high2float(h01);
            const float c2v = __low2float(h2x);
            // packed over the two pixels:
            const f2 dz  = (f2)(A.w) - cz2;
            const f2 dot = (f2)(A.x) * cnx2 + ((f2)(A.y) * cny2 + (f2)(A.z) * cnz2);
            f2 c = __builtin_elementwise_max(dot, (f2)(0.f));
            c = __builtin_elementwise_min(c, (f2)(1.f));
            f2 s = c * c;                      // exact c^128: 7 pk_mul
            s = s * s; s = s * s; s = s * s;
            s = s * s; s = s * s; s = s * s;
            const f2 r   = __builtin_elementwise_max(ic2 * rdz2, (f2)(RCLAMP));
            const f2 ad  = __builtin_elementwise_abs(dz);
            const f2 arg = ad * r + lw2;
            f2 w;
            w.x = __builtin_amdgcn_exp2f(arg.x);
            w.y = __builtin_amdgcn_exp2f(arg.y);
            w *= s;
            ax2 = (f2)(c0)  * w + ax2;
            ay2 = (f2)(c1)  * w + ay2;
            az2 = (f2)(c2v) * w + az2;
            aw2 += w;
        }
    }

    // ---- epilogue: out = accum_col / max(accum_w, EPS) ----
#pragma unroll
    for (int p = 0; p < PY; ++p) {
        const int gy = by0 + ty * PY + p;
        if (gy < IMG_H) {
            const float aw = (p == 0) ? aw2.x : aw2.y;
            const float inv = __builtin_amdgcn_rcpf(fmaxf(aw, 1e-4f));
            const int o = (gy * IMG_W + gx) * 3;
            out[o + 0] = ((p == 0) ? ax2.x : ax2.y) * inv;
            out[o + 1] = ((p == 0) ? ay2.x : ay2.y) * inv;
            out[o + 2] = ((p == 0) ? az2.x : az2.y) * inv;
        }
    }
}

extern "C" void kernel_launch(void* const* d_in, const int* in_sizes, int n_in,
                              void* d_out, int out_size, void* d_ws, size_t ws_size,
                              hipStream_t stream) {
    const float* in = (const float*)d_in[0];
    float* out = (float*)d_out;
    dim3 grid(IMG_W / TLX, (IMG_H + TLY - 1) / TLY);   // 60 x 68
    dim3 block(32, 8);
    hipLaunchKernelGGL(bilateral_denoise_kernel, grid, block, 0, stream, in, out);
}

// Round 7
// 311.380 us; speedup vs baseline: 1.1024x; 1.1024x over previous
//
#include <hip/hip_runtime.h>

// Bilateral denoiser, 1080x1920x11 fp32 -> 1080x1920x3 fp32.
// d^2 <= 36 (113 taps; tighter pruning FAILS: epilogue ratio amplifies
// weight error by 1/EPS=1e4). Exact c^128 via 7 packed squarings (approx
// pow also FAILS, same amplifier). PY=2 y-stacked px/thread in v_pk_*_f32.
// BRANCHLESS inner loop: all 13 dx execute; masked taps get lwK=-1e30 from
// the wave-uniform constant table -> w=0 exactly; no s_cbranch fences so
// the 13 ds_read_b128 pairs batch and hide the ~120cyc LDS latency.
// __launch_bounds__(256,4): (256,5) forced a 48-VGPR allocation that
// spilled ~346MB/launch to scratch (R6: WRITE_SIZE 24->370MB, dur 264us).
// Tile 32x16, block (32,8), LDS 39.4KB -> 4 blocks/CU (16 waves).

namespace {
constexpr int IMG_H = 1080;
constexpr int IMG_W = 1920;
constexpr int CHN   = 11;
constexpr int TLX   = 32;
constexpr int TLY   = 16;
constexpr int HALO  = 6;
constexpr int RX    = TLX + 2 * HALO;   // 44
constexpr int RY    = TLY + 2 * HALO;   // 28
constexpr int PY    = 2;
constexpr int R2MAX = 36;

constexpr double CD = -1.4426950408889634;   // -log2(e)

struct alignas(16) Tab {
    // [j+6][dx+6] -> {invdC p0, invdC p1, lwK p0, lwK p1}; dy_p = j - p
    float v[14][13][4];
    constexpr Tab() : v{} {
        for (int jj = 0; jj < 14; ++jj)
            for (int di = 0; di < 13; ++di)
                for (int p = 0; p < 2; ++p) {
                    const int dy = (jj - 6) - p, dx = di - 6;
                    const int d2 = dy * dy + dx * dx;
                    float ic, lwk;
                    if (d2 == 0) {            // center: ad==0; huge ic -> clamp
                        ic = -1e30f; lwk = 0.f;
                    } else if (d2 <= R2MAX) { // active tap
                        double s = (double)d2, x = s;
                        for (int it = 0; it < 60; ++it) x = 0.5 * (x + s / x);
                        ic  = (float)(CD / x);
                        lwk = (float)(0.5 * CD * d2);
                    } else {                  // masked: w forced to exactly 0
                        ic = (float)CD; lwk = -1e30f;
                    }
                    v[jj][di][p]     = ic;
                    v[jj][di][2 + p] = lwk;
                }
    }
};
}
__constant__ Tab TAB;

typedef float f2 __attribute__((ext_vector_type(2)));

__global__ __launch_bounds__(256, 4)
void bilateral_denoise_kernel(const float* __restrict__ in, float* __restrict__ out) {
    __shared__ float4 ldsA[RY * RX];  // {col0, col1, col2, z}
    __shared__ float4 ldsB[RY * RX];  // {nrm0, nrm1, nrm2, 0}

    const int lx  = threadIdx.x;
    const int ty  = threadIdx.y;
    const int bx0 = blockIdx.x * TLX;
    const int by0 = blockIdx.y * TLY;
    const int tid = ty * 32 + lx;

    // ---- stage tile + halo (OOB -> zeros => dot=0 => c^128=0 => w=0) ----
    for (int r = tid; r < RY * RX; r += 256) {
        const int ry = r / RX;
        const int rx = r - ry * RX;
        const int gy = by0 - HALO + ry;
        const int gx = bx0 - HALO + rx;
        float4 A = make_float4(0.f, 0.f, 0.f, 0.f);
        float4 B = make_float4(0.f, 0.f, 0.f, 0.f);
        if ((unsigned)gy < (unsigned)IMG_H && (unsigned)gx < (unsigned)IMG_W) {
            const float* p = in + (gy * IMG_W + gx) * CHN;
            A.x = p[0]; A.y = p[1]; A.z = p[2]; A.w = p[9];
            B.x = p[3]; B.y = p[4]; B.z = p[5];
        }
        ldsA[r] = A;
        ldsB[r] = B;
    }
    __syncthreads();

    // ---- per-thread center state: 2 px packed as one f2 pair ----
    const int gx = bx0 + lx;
    const int crow = (ty * PY + HALO) * RX + HALO + lx;
    const float4 CA0 = ldsA[crow];
    const float4 CA1 = ldsA[crow + RX];
    const float4 CB0 = ldsB[crow];
    const float4 CB1 = ldsB[crow + RX];
    const f2 cnx2 = {CB0.x, CB1.x};
    const f2 cny2 = {CB0.y, CB1.y};
    const f2 cnz2 = {CB0.z, CB1.z};
    const f2 cz2  = {CA0.w, CA1.w};
    f2 rdz2;
#pragma unroll
    for (int p = 0; p < PY; ++p) {
        const int gy = by0 + ty * PY + p;
        float dzv = 0.f;
        if (gy < IMG_H) dzv = in[(gy * IMG_W + gx) * CHN + 10];
        // dz<=0 -> rcp(0)=+inf -> rrc=-inf -> clamp to CD/EPS == 1/max(.,EPS)
        const float rv = __builtin_amdgcn_rcpf(fmaxf(dzv, 0.f));
        if (p == 0) rdz2.x = rv; else rdz2.y = rv;
    }
    f2 ax2 = (f2)(0.f), ay2 = (f2)(0.f), az2 = (f2)(0.f), aw2 = (f2)(0.f);

    const float RCLAMP = -14426.9504f;   // CD * 1e4 (== CD/EPS)

    // j = dy + p; no inner branches — table masks inactive taps (w=0).
#pragma unroll 1
    for (int j = -HALO; j <= HALO + PY - 1; ++j) {   // 14 rows
        const int rowb = (ty * PY + HALO + j) * RX + HALO + lx;
        const float* trow = &TAB.v[j + 6][0][0];
#pragma unroll
        for (int dxi = 0; dxi < 13; ++dxi) {
            const int dx = dxi - 6;
            const float4 T4 = *(const float4*)(trow + dxi * 4);   // s_load_x4
            const f2 ic2 = {T4.x, T4.y};
            const f2 lw2 = {T4.z, T4.w};
            const float4 A = ldsA[rowb + dx];                     // ds_read_b128
            const float4 B = ldsB[rowb + dx];                     // ds_read_b128
            // packed over the two pixels:
            const f2 dz  = (f2)(A.w) - cz2;
            const f2 dot = (f2)(B.x) * cnx2 + ((f2)(B.y) * cny2 + (f2)(B.z) * cnz2);
            f2 c = __builtin_elementwise_max(dot, (f2)(0.f));
            c = __builtin_elementwise_min(c, (f2)(1.f));
            f2 s = c * c;                      // exact c^128: 7 pk_mul
            s = s * s; s = s * s; s = s * s;
            s = s * s; s = s * s; s = s * s;
            const f2 r   = __builtin_elementwise_max(ic2 * rdz2, (f2)(RCLAMP));
            const f2 ad  = __builtin_elementwise_abs(dz);
            const f2 arg = ad * r + lw2;
            f2 w;
            w.x = __builtin_amdgcn_exp2f(arg.x);
            w.y = __builtin_amdgcn_exp2f(arg.y);
            w *= s;
            ax2 = (f2)(A.x) * w + ax2;
            ay2 = (f2)(A.y) * w + ay2;
            az2 = (f2)(A.z) * w + az2;
            aw2 += w;
        }
    }

    // ---- epilogue: out = accum_col / max(accum_w, EPS) ----
#pragma unroll
    for (int p = 0; p < PY; ++p) {
        const int gy = by0 + ty * PY + p;
        if (gy < IMG_H) {
            const float aw = (p == 0) ? aw2.x : aw2.y;
            const float inv = __builtin_amdgcn_rcpf(fmaxf(aw, 1e-4f));
            const int o = (gy * IMG_W + gx) * 3;
            out[o + 0] = ((p == 0) ? ax2.x : ax2.y) * inv;
            out[o + 1] = ((p == 0) ? ay2.x : ay2.y) * inv;
            out[o + 2] = ((p == 0) ? az2.x : az2.y) * inv;
        }
    }
}

extern "C" void kernel_launch(void* const* d_in, const int* in_sizes, int n_in,
                              void* d_out, int out_size, void* d_ws, size_t ws_size,
                              hipStream_t stream) {
    const float* in = (const float*)d_in[0];
    float* out = (float*)d_out;
    dim3 grid(IMG_W / TLX, (IMG_H + TLY - 1) / TLY);   // 60 x 68
    dim3 block(32, 8);
    hipLaunchKernelGGL(bilateral_denoise_kernel, grid, block, 0, stream, in, out);
}

// Round 8
// 240.360 us; speedup vs baseline: 1.4282x; 1.2955x over previous
//
#include <hip/hip_runtime.h>
#include <hip/hip_fp16.h>

// Bilateral denoiser, 1080x1920x11 fp32 -> 1080x1920x3 fp32.
// d^2 <= 36 (113 taps; tighter pruning FAILS: epilogue ratio amplifies
// weight error by 1/EPS=1e4). Exact c^128 via 7 packed squarings (approx
// pow also FAILS, same amplifier). PY=2 y-stacked px/thread in v_pk_*_f32.
// BRANCHY pair-gated inner loop (R3-proven): branchless 13-wide bodies
// spill (R6: 346MB, R7: 186MB scratch traffic) — do not revisit.
// Colors fp16 in LDS (linear in output, rel err ~5e-4 -> safe; z stays
// fp32 — fp16 z breaks in the 1/EPS amplifier zone). 24 B/px -> LDS
// 29.6 KB -> 5 blocks/CU (20 waves) vs R3's 4 blocks. launch_bounds stays
// (256,4): forcing 5 via launch_bounds caps VGPR and spills (R6).

namespace {
constexpr int IMG_H = 1080;
constexpr int IMG_W = 1920;
constexpr int CHN   = 11;
constexpr int TLX   = 32;
constexpr int TLY   = 16;
constexpr int HALO  = 6;
constexpr int RX    = TLX + 2 * HALO;   // 44
constexpr int RY    = TLY + 2 * HALO;   // 28
constexpr int PY    = 2;
constexpr int R2MAX = 36;

constexpr double CD = -1.4426950408889634;   // -log2(e)

struct alignas(16) Tab {
    // [j+6][dx+6] -> {invdC p0, invdC p1, lwK p0, lwK p1}; dy_p = j - p
    float v[14][13][4];
    constexpr Tab() : v{} {
        for (int jj = 0; jj < 14; ++jj)
            for (int di = 0; di < 13; ++di)
                for (int p = 0; p < 2; ++p) {
                    const int dy = (jj - 6) - p, dx = di - 6;
                    const int d2 = dy * dy + dx * dx;
                    float ic, lwk;
                    if (d2 == 0) {            // center: ad==0; huge ic -> clamp
                        ic = -1e30f; lwk = 0.f;
                    } else if (d2 <= R2MAX) { // active tap
                        double s = (double)d2, x = s;
                        for (int it = 0; it < 60; ++it) x = 0.5 * (x + s / x);
                        ic  = (float)(CD / x);
                        lwk = (float)(0.5 * CD * d2);
                    } else {                  // masked: w forced to exactly 0
                        ic = (float)CD; lwk = -1e30f;
                    }
                    v[jj][di][p]     = ic;
                    v[jj][di][2 + p] = lwk;
                }
    }
};
}
__constant__ Tab TAB;

typedef float f2 __attribute__((ext_vector_type(2)));

__global__ __launch_bounds__(256, 4)
void bilateral_denoise_kernel(const float* __restrict__ in, float* __restrict__ out) {
    __shared__ float4  ldsA[RY * RX];       // {nrm0, nrm1, nrm2, z}  16 B
    __shared__ __half2 ldsC[RY * RX][2];    // {col01, col2_}          8 B

    const int lx  = threadIdx.x;
    const int ty  = threadIdx.y;
    const int bx0 = blockIdx.x * TLX;
    const int by0 = blockIdx.y * TLY;
    const int tid = ty * 32 + lx;

    // ---- stage tile + halo (OOB -> zeros => dot=0 => c^128=0 => w=0) ----
    for (int r = tid; r < RY * RX; r += 256) {
        const int ry = r / RX;
        const int rx = r - ry * RX;
        const int gy = by0 - HALO + ry;
        const int gx = bx0 - HALO + rx;
        float4 A = make_float4(0.f, 0.f, 0.f, 0.f);
        float c0 = 0.f, c1 = 0.f, c2 = 0.f;
        if ((unsigned)gy < (unsigned)IMG_H && (unsigned)gx < (unsigned)IMG_W) {
            const float* p = in + (gy * IMG_W + gx) * CHN;
            c0 = p[0]; c1 = p[1]; c2 = p[2];
            A.x = p[3]; A.y = p[4]; A.z = p[5]; A.w = p[9];
        }
        ldsA[r] = A;
        ldsC[r][0] = __floats2half2_rn(c0, c1);
        ldsC[r][1] = __floats2half2_rn(c2, 0.f);
    }
    __syncthreads();

    // ---- per-thread center state: 2 px packed as one f2 pair ----
    const int gx = bx0 + lx;
    const int crow = (ty * PY + HALO) * RX + HALO + lx;
    const float4 CA0 = ldsA[crow];
    const float4 CA1 = ldsA[crow + RX];
    const f2 cnx2 = {CA0.x, CA1.x};
    const f2 cny2 = {CA0.y, CA1.y};
    const f2 cnz2 = {CA0.z, CA1.z};
    const f2 cz2  = {CA0.w, CA1.w};
    f2 rdz2;
#pragma unroll
    for (int p = 0; p < PY; ++p) {
        const int gy = by0 + ty * PY + p;
        float dzv = 0.f;
        if (gy < IMG_H) dzv = in[(gy * IMG_W + gx) * CHN + 10];
        // dz<=0 -> rcp(0)=+inf -> rrc=-inf -> clamp to CD/EPS == 1/max(.,EPS)
        const float rv = __builtin_amdgcn_rcpf(fmaxf(dzv, 0.f));
        if (p == 0) rdz2.x = rv; else rdz2.y = rv;
    }
    f2 ax2 = (f2)(0.f), ay2 = (f2)(0.f), az2 = (f2)(0.f), aw2 = (f2)(0.f);

    const float RCLAMP = -14426.9504f;   // CD * 1e4 (== CD/EPS)

    // j = dy + p; pair-level uniform gate, per-p masking via table (lwK=-1e30).
#pragma unroll 1
    for (int j = -HALO; j <= HALO + PY - 1; ++j) {   // 14 rows
        const int dy0 = j, dy1 = j - 1;
        const int m0 = R2MAX - dy0 * dy0;
        const int m1 = R2MAX - dy1 * dy1;
        const int m2 = m0 > m1 ? m0 : m1;
        const int rowb = (ty * PY + HALO + j) * RX + HALO + lx;
        const float* trow = &TAB.v[j + 6][0][0];
#pragma unroll
        for (int dxi = 0; dxi < 13; ++dxi) {
            const int dx = dxi - 6;
            if (dx * dx <= m2) {                      // uniform scalar branch
                const float4 T4 = *(const float4*)(trow + dxi * 4);   // s_load
                const f2 ic2 = {T4.x, T4.y};
                const f2 lw2 = {T4.z, T4.w};
                const float4 A = ldsA[rowb + dx];                     // b128
                const __half2 h01 = ldsC[rowb + dx][0];               // b64
                const __half2 h2x = ldsC[rowb + dx][1];
                const float c0  = __low2float(h01);
                const float c1  = __high2float(h01);
                const float c2v = __low2float(h2x);
                // packed over the two pixels:
                const f2 dz  = (f2)(A.w) - cz2;
                const f2 dot = (f2)(A.x) * cnx2 + ((f2)(A.y) * cny2 + (f2)(A.z) * cnz2);
                f2 c = __builtin_elementwise_max(dot, (f2)(0.f));
                c = __builtin_elementwise_min(c, (f2)(1.f));
                f2 s = c * c;                      // exact c^128: 7 pk_mul
                s = s * s; s = s * s; s = s * s;
                s = s * s; s = s * s; s = s * s;
                const f2 r   = __builtin_elementwise_max(ic2 * rdz2, (f2)(RCLAMP));
                const f2 ad  = __builtin_elementwise_abs(dz);
                const f2 arg = ad * r + lw2;
                f2 w;
                w.x = __builtin_amdgcn_exp2f(arg.x);
                w.y = __builtin_amdgcn_exp2f(arg.y);
                w *= s;
                ax2 = (f2)(c0)  * w + ax2;
                ay2 = (f2)(c1)  * w + ay2;
                az2 = (f2)(c2v) * w + az2;
                aw2 += w;
            }
        }
    }

    // ---- epilogue: out = accum_col / max(accum_w, EPS) ----
#pragma unroll
    for (int p = 0; p < PY; ++p) {
        const int gy = by0 + ty * PY + p;
        if (gy < IMG_H) {
            const float aw = (p == 0) ? aw2.x : aw2.y;
            const float inv = __builtin_amdgcn_rcpf(fmaxf(aw, 1e-4f));
            const int o = (gy * IMG_W + gx) * 3;
            out[o + 0] = ((p == 0) ? ax2.x : ax2.y) * inv;
            out[o + 1] = ((p == 0) ? ay2.x : ay2.y) * inv;
            out[o + 2] = ((p == 0) ? az2.x : az2.y) * inv;
        }
    }
}

extern "C" void kernel_launch(void* const* d_in, const int* in_sizes, int n_in,
                              void* d_out, int out_size, void* d_ws, size_t ws_size,
                              hipStream_t stream) {
    const float* in = (const float*)d_in[0];
    float* out = (float*)d_out;
    dim3 grid(IMG_W / TLX, (IMG_H + TLY - 1) / TLY);   // 60 x 68
    dim3 block(32, 8);
    hipLaunchKernelGGL(bilateral_denoise_kernel, grid, block, 0, stream, in, out);
}